// Round 1
// baseline (7676.649 us; speedup 1.0000x reference)
//
#include <hip/hip_runtime.h>

// Problem constants (from reference)
#define N_ROWS 32768      // 16*2048 query vectors
#define D_DIM  256        // embedding dim
#define K_CODES 8192      // codebook size
#define NPART  8          // K partitions for argmin kernel
#define CPP    (K_CODES / NPART)   // codes per partition = 1024
#define TC     32         // codes per register tile
#define DC     32         // d-chunk held in VGPRs per lane

// Output layout (flat float32, reference return order)
#define OUT0_OFF 0                     // z_q_st [16,2048,256]
#define OUT1_OFF 8388608               // z_q    [16,2048,256]
#define OUTI_OFF 16777216              // indices [16,2048] (as float)
#define OUTS_OFF 16809984              // stats [2]

// ---------------------------------------------------------------------------
// Kernel 1: codebook row norms ||e_k||^2 + zero the usage histogram.
// grid: K_CODES/4 blocks x 256 threads (1 wave per code row).
__global__ __launch_bounds__(256) void vq_norms_zero(const float* __restrict__ E,
                                                     float* __restrict__ norms,
                                                     int* __restrict__ usage) {
    const int wave = threadIdx.x >> 6;
    const int lane = threadIdx.x & 63;
    const int code = blockIdx.x * 4 + wave;
    float4 v = ((const float4*)(E + code * D_DIM))[lane];  // 64 lanes * 4 = 256
    float s = v.x * v.x + v.y * v.y + v.z * v.z + v.w * v.w;
    #pragma unroll
    for (int off = 32; off >= 1; off >>= 1) s += __shfl_down(s, off);
    if (lane == 0) norms[code] = s;
    if (blockIdx.x < K_CODES / 256) usage[blockIdx.x * 256 + threadIdx.x] = 0;
}

// ---------------------------------------------------------------------------
// Kernel 2: transpose z_e [N,D] -> xT [D,N] (so per-row register loads in the
// argmin kernel are lane-coalesced). xT lives in the out0 region of d_out,
// which the finalize kernel fully overwrites afterwards.
__global__ __launch_bounds__(256) void vq_transpose(const float* __restrict__ x,
                                                    float* __restrict__ xT) {
    __shared__ float tile[32][33];  // +1 pad: bank-conflict-free transpose
    const int n0 = blockIdx.x * 32;
    const int d0 = blockIdx.y * 32;
    const int tx = threadIdx.x;     // 0..31
    const int ty = threadIdx.y;     // 0..7
    #pragma unroll
    for (int i = 0; i < 32; i += 8)
        tile[ty + i][tx] = x[(size_t)(n0 + ty + i) * D_DIM + d0 + tx];
    __syncthreads();
    #pragma unroll
    for (int i = 0; i < 32; i += 8)
        xT[(size_t)(d0 + ty + i) * N_ROWS + n0 + tx] = tile[tx][ty + i];
}

// ---------------------------------------------------------------------------
// Kernel 3: fused score + partial argmin. Each lane owns one x-row.
// Codebook values are wave-uniform -> SGPR broadcast (s_load), inner loop is
// pure v_fmac_f32 with SGPR src: no LDS, VALU-bound.
// grid: (N_ROWS/256, NPART) x 256 threads.
__global__ __launch_bounds__(256, 4) void vq_argmin(const float* __restrict__ xT,
                                                    const float* __restrict__ E,
                                                    const float* __restrict__ norms,
                                                    float* __restrict__ pv,
                                                    int* __restrict__ pi) {
    const int row = blockIdx.x * 256 + threadIdx.x;
    const int cbase0 = blockIdx.y * CPP;

    float bestv = 3.4e38f;
    int besti = 0;

    for (int t = 0; t < CPP / TC; ++t) {
        const int cbase = cbase0 + t * TC;
        float acc[TC];
        #pragma unroll
        for (int c = 0; c < TC; ++c) acc[c] = 0.0f;

        for (int ch = 0; ch < D_DIM / DC; ++ch) {
            // per-lane x chunk: coalesced dword loads from xT
            float xr[DC];
            #pragma unroll
            for (int d = 0; d < DC; ++d)
                xr[d] = xT[(size_t)(ch * DC + d) * N_ROWS + row];

            #pragma unroll
            for (int c = 0; c < TC; ++c) {
                const float* ep = E + (size_t)(cbase + c) * D_DIM + ch * DC;
                #pragma unroll
                for (int d = 0; d < DC; ++d)
                    acc[c] = fmaf(ep[d], xr[d], acc[c]);   // s_e * v_x
            }
        }

        #pragma unroll
        for (int c = 0; c < TC; ++c) {
            // score = ||e||^2 - 2 x.e   (||x||^2 dropped: row-constant)
            float sc = norms[cbase + c] - 2.0f * acc[c];
            if (sc < bestv) { bestv = sc; besti = cbase + c; }
        }
    }

    pv[row * NPART + blockIdx.y] = bestv;
    pi[row * NPART + blockIdx.y] = besti;
}

// ---------------------------------------------------------------------------
// Kernel 4: per-row reduce of NPART partials, gather codebook row to both
// z_q_st and z_q outputs, emit index (as float), bump usage histogram.
// grid: N_ROWS blocks x 64 threads.
__global__ __launch_bounds__(64) void vq_finalize(const float* __restrict__ pv,
                                                  const int* __restrict__ pi,
                                                  const float* __restrict__ E,
                                                  float* __restrict__ out0,
                                                  float* __restrict__ out1,
                                                  float* __restrict__ outI,
                                                  int* __restrict__ usage) {
    const int row = blockIdx.x;
    const int lane = threadIdx.x;  // 0..63
    float v = 3.4e38f;
    int idx = 0x7fffffff;
    if (lane < NPART) {
        v = pv[row * NPART + lane];
        idx = pi[row * NPART + lane];
    }
    #pragma unroll
    for (int off = 4; off >= 1; off >>= 1) {
        float ov = __shfl_down(v, off);
        int   oi = __shfl_down(idx, off);
        if (ov < v || (ov == v && oi < idx)) { v = ov; idx = oi; }
    }
    idx = __shfl(idx, 0);

    float4 e4 = ((const float4*)(E + (size_t)idx * D_DIM))[lane];
    ((float4*)(out0 + (size_t)row * D_DIM))[lane] = e4;
    ((float4*)(out1 + (size_t)row * D_DIM))[lane] = e4;
    if (lane == 0) {
        outI[row] = (float)idx;
        atomicAdd(&usage[idx], 1);
    }
}

// ---------------------------------------------------------------------------
// Kernel 5: perplexity + dead ratio from histogram. Single block.
__global__ __launch_bounds__(256) void vq_stats(const int* __restrict__ usage,
                                                float* __restrict__ statsOut) {
    __shared__ float redp[256];
    __shared__ int   redz[256];
    const int t = threadIdx.x;
    float pl = 0.0f;
    int zc = 0;
    for (int i = t; i < K_CODES; i += 256) {
        const int u = usage[i];
        if (u == 0) {
            zc++;
        } else {
            // total = max(sum(usage),1) = N_ROWS (every row counted once)
            const float p = (float)u * (1.0f / (float)N_ROWS);
            pl += p * logf(p);
        }
    }
    redp[t] = pl;
    redz[t] = zc;
    __syncthreads();
    for (int s = 128; s > 0; s >>= 1) {
        if (t < s) { redp[t] += redp[t + s]; redz[t] += redz[t + s]; }
        __syncthreads();
    }
    if (t == 0) {
        statsOut[0] = expf(-redp[0]);                     // perplexity
        statsOut[1] = (float)redz[0] / (float)K_CODES;    // dead ratio
    }
}

// ---------------------------------------------------------------------------
extern "C" void kernel_launch(void* const* d_in, const int* in_sizes, int n_in,
                              void* d_out, int out_size, void* d_ws, size_t ws_size,
                              hipStream_t stream) {
    const float* z_e = (const float*)d_in[0];   // [16,2048,256] f32
    const float* E   = (const float*)d_in[1];   // [8192,256] f32

    float* out  = (float*)d_out;
    float* out0 = out + OUT0_OFF;
    float* out1 = out + OUT1_OFF;
    float* outI = out + OUTI_OFF;
    float* outS = out + OUTS_OFF;

    char* ws = (char*)d_ws;
    float* norms = (float*)ws;                                   // 32 KB
    int*   usage = (int*)(ws + 32768);                           // 32 KB
    float* pv    = (float*)(ws + 65536);                         // 1 MB
    int*   pi    = (int*)(ws + 65536 + sizeof(float) * N_ROWS * NPART);  // 1 MB

    // xT scratch aliases out0 (exactly 8.4M floats); finalize overwrites it.
    float* xT = out0;

    vq_norms_zero<<<dim3(K_CODES / 4), dim3(256), 0, stream>>>(E, norms, usage);
    vq_transpose<<<dim3(N_ROWS / 32, D_DIM / 32), dim3(32, 8), 0, stream>>>(z_e, xT);
    vq_argmin<<<dim3(N_ROWS / 256, NPART), dim3(256), 0, stream>>>(xT, E, norms, pv, pi);
    vq_finalize<<<dim3(N_ROWS), dim3(64), 0, stream>>>(pv, pi, E, out0, out1, outI, usage);
    vq_stats<<<dim3(1), dim3(256), 0, stream>>>(usage, outS);
}

// Round 2
// 6201.971 us; speedup vs baseline: 1.2378x; 1.2378x over previous
//
#include <hip/hip_runtime.h>

// Problem constants (from reference)
#define N_ROWS 32768      // 16*2048 query vectors
#define D_DIM  256        // embedding dim
#define K_CODES 8192      // codebook size
#define NPART  8          // K partitions for argmin kernel
#define CPP    (K_CODES / NPART)   // codes per partition = 1024
#define TC     16         // codes per register tile (acc[16] + xr[32] fits in VGPRs)
#define NCH    8          // d-chunks of 32

// Output layout (flat float32, reference return order)
#define OUT0_OFF 0                     // z_q_st [16,2048,256]
#define OUT1_OFF 8388608               // z_q    [16,2048,256]
#define OUTI_OFF 16777216              // indices [16,2048] (as float)
#define OUTS_OFF 16809984              // stats [2]

// Constant-address-space cast: forces uniform loads to s_load_* (SMEM pipe),
// freeing the VALU for pure v_fmac. (Same trick as CK's
// cast_pointer_to_constant_address_space.)
typedef __attribute__((address_space(4))) const float kfloat;

// ---------------------------------------------------------------------------
// Kernel 1: codebook row norms ||e_k||^2 + zero the usage histogram.
__global__ __launch_bounds__(256) void vq_norms_zero(const float* __restrict__ E,
                                                     float* __restrict__ norms,
                                                     int* __restrict__ usage) {
    const int wave = threadIdx.x >> 6;
    const int lane = threadIdx.x & 63;
    const int code = blockIdx.x * 4 + wave;
    float4 v = ((const float4*)(E + code * D_DIM))[lane];  // 64 lanes * 4 = 256
    float s = v.x * v.x + v.y * v.y + v.z * v.z + v.w * v.w;
    #pragma unroll
    for (int off = 32; off >= 1; off >>= 1) s += __shfl_down(s, off);
    if (lane == 0) norms[code] = s;
    if (blockIdx.x < K_CODES / 256) usage[blockIdx.x * 256 + threadIdx.x] = 0;
}

// ---------------------------------------------------------------------------
// Kernel 2: re-layout z_e [N,D] -> xC [D/32][N][32] (chunked): each row's
// 32-float d-chunk is contiguous (128 B) so the argmin kernel loads it as
// 8x global_load_dwordx4 from ONE base address (offset immediates).
// Pure index-shuffle copy; both sides move in >=128 B dense segments.
__global__ __launch_bounds__(256) void vq_xchunk(const float* __restrict__ x,
                                                 float* __restrict__ xC) {
    const size_t tid = (size_t)blockIdx.x * 256 + threadIdx.x;  // over 2,097,152 float4s
    const size_t w = tid * 4;                 // write offset (floats), fully linear
    const int dd = (int)(w & 31);             // 0,4,...,28
    const size_t rowchunk = w >> 5;           // chunk * N_ROWS + row
    const int chunk = (int)(rowchunk >> 15);  // N_ROWS = 2^15
    const int row = (int)(rowchunk & (N_ROWS - 1));
    const float4 v = *(const float4*)(x + (size_t)row * D_DIM + chunk * 32 + dd);
    *(float4*)(xC + w) = v;
}

// ---------------------------------------------------------------------------
// Kernel 3: fused score + partial argmin. Each lane owns one x-row (32-float
// chunk in VGPRs, reloaded per tile); codebook values arrive via the scalar
// pipe (s_load from addrspace(4)) -> inner loop is v_fmac_f32 v, s, v.
// grid: (N_ROWS/256, NPART) x 256 threads.
__global__ __launch_bounds__(256, 4) void vq_argmin(const float* __restrict__ xC,
                                                    const float* __restrict__ E,
                                                    const float* __restrict__ norms,
                                                    float* __restrict__ pv,
                                                    int* __restrict__ pi) {
    const int row = blockIdx.x * 256 + threadIdx.x;
    const int cbase0 = blockIdx.y * CPP;
    kfloat* Ec = (kfloat*)E;
    kfloat* Nc = (kfloat*)norms;

    float bestv = 3.4e38f;
    int besti = 0;

    for (int t = 0; t < CPP / TC; ++t) {   // 64 tiles of 16 codes
        const int cbase = cbase0 + t * TC;
        float acc[TC];
        #pragma unroll
        for (int c = 0; c < TC; ++c) acc[c] = 0.0f;

        for (int ch = 0; ch < NCH; ++ch) {
            // per-lane x chunk: 8x dwordx4 from one base (offset:0..112)
            float4 xr[8];
            const float4* xp = (const float4*)(xC + ((size_t)ch * N_ROWS + row) * 32);
            #pragma unroll
            for (int q = 0; q < 8; ++q) xr[q] = xp[q];

            #pragma unroll
            for (int c = 0; c < TC; ++c) {
                kfloat* ep = Ec + (size_t)(cbase + c) * D_DIM + ch * 32;
                #pragma unroll
                for (int q = 0; q < 8; ++q) {
                    acc[c] = fmaf(ep[4 * q + 0], xr[q].x, acc[c]);
                    acc[c] = fmaf(ep[4 * q + 1], xr[q].y, acc[c]);
                    acc[c] = fmaf(ep[4 * q + 2], xr[q].z, acc[c]);
                    acc[c] = fmaf(ep[4 * q + 3], xr[q].w, acc[c]);
                }
            }
        }

        #pragma unroll
        for (int c = 0; c < TC; ++c) {
            // score = ||e||^2 - 2 x.e   (||x||^2 dropped: row-constant)
            float sc = Nc[cbase + c] - 2.0f * acc[c];
            if (sc < bestv) { bestv = sc; besti = cbase + c; }  // '<' keeps first (lowest idx)
        }
    }

    pv[row * NPART + blockIdx.y] = bestv;
    pi[row * NPART + blockIdx.y] = besti;
}

// ---------------------------------------------------------------------------
// Kernel 4: per-row reduce of NPART partials, gather codebook row to both
// z_q_st and z_q outputs, emit index (as float), bump usage histogram.
__global__ __launch_bounds__(64) void vq_finalize(const float* __restrict__ pv,
                                                  const int* __restrict__ pi,
                                                  const float* __restrict__ E,
                                                  float* __restrict__ out0,
                                                  float* __restrict__ out1,
                                                  float* __restrict__ outI,
                                                  int* __restrict__ usage) {
    const int row = blockIdx.x;
    const int lane = threadIdx.x;  // 0..63
    float v = 3.4e38f;
    int idx = 0x7fffffff;
    if (lane < NPART) {
        v = pv[row * NPART + lane];
        idx = pi[row * NPART + lane];
    }
    #pragma unroll
    for (int off = 4; off >= 1; off >>= 1) {
        float ov = __shfl_down(v, off);
        int   oi = __shfl_down(idx, off);
        if (ov < v || (ov == v && oi < idx)) { v = ov; idx = oi; }
    }
    idx = __shfl(idx, 0);

    float4 e4 = ((const float4*)(E + (size_t)idx * D_DIM))[lane];
    ((float4*)(out0 + (size_t)row * D_DIM))[lane] = e4;
    ((float4*)(out1 + (size_t)row * D_DIM))[lane] = e4;
    if (lane == 0) {
        outI[row] = (float)idx;
        atomicAdd(&usage[idx], 1);
    }
}

// ---------------------------------------------------------------------------
// Kernel 5: perplexity + dead ratio from histogram. Single block.
__global__ __launch_bounds__(256) void vq_stats(const int* __restrict__ usage,
                                                float* __restrict__ statsOut) {
    __shared__ float redp[256];
    __shared__ int   redz[256];
    const int t = threadIdx.x;
    float pl = 0.0f;
    int zc = 0;
    for (int i = t; i < K_CODES; i += 256) {
        const int u = usage[i];
        if (u == 0) {
            zc++;
        } else {
            // total = max(sum(usage),1) = N_ROWS (every row counted once)
            const float p = (float)u * (1.0f / (float)N_ROWS);
            pl += p * logf(p);
        }
    }
    redp[t] = pl;
    redz[t] = zc;
    __syncthreads();
    for (int s = 128; s > 0; s >>= 1) {
        if (t < s) { redp[t] += redp[t + s]; redz[t] += redz[t + s]; }
        __syncthreads();
    }
    if (t == 0) {
        statsOut[0] = expf(-redp[0]);                     // perplexity
        statsOut[1] = (float)redz[0] / (float)K_CODES;    // dead ratio
    }
}

// ---------------------------------------------------------------------------
extern "C" void kernel_launch(void* const* d_in, const int* in_sizes, int n_in,
                              void* d_out, int out_size, void* d_ws, size_t ws_size,
                              hipStream_t stream) {
    const float* z_e = (const float*)d_in[0];   // [16,2048,256] f32
    const float* E   = (const float*)d_in[1];   // [8192,256] f32

    float* out  = (float*)d_out;
    float* out0 = out + OUT0_OFF;
    float* out1 = out + OUT1_OFF;
    float* outI = out + OUTI_OFF;
    float* outS = out + OUTS_OFF;

    char* ws = (char*)d_ws;
    float* norms = (float*)ws;                                   // 32 KB
    int*   usage = (int*)(ws + 32768);                           // 32 KB
    float* pv    = (float*)(ws + 65536);                         // 1 MB
    int*   pi    = (int*)(ws + 65536 + sizeof(float) * N_ROWS * NPART);  // 1 MB

    // xC scratch aliases out0 (exactly 8.4M floats); finalize overwrites it.
    float* xC = out0;

    vq_norms_zero<<<dim3(K_CODES / 4), dim3(256), 0, stream>>>(E, norms, usage);
    vq_xchunk<<<dim3((N_ROWS * D_DIM / 4) / 256), dim3(256), 0, stream>>>(z_e, xC);
    vq_argmin<<<dim3(N_ROWS / 256, NPART), dim3(256), 0, stream>>>(xC, E, norms, pv, pi);
    vq_finalize<<<dim3(N_ROWS), dim3(64), 0, stream>>>(pv, pi, E, out0, out1, outI, usage);
    vq_stats<<<dim3(1), dim3(256), 0, stream>>>(usage, outS);
}

// Round 3
// 1126.217 us; speedup vs baseline: 6.8163x; 5.5069x over previous
//
#include <hip/hip_runtime.h>

// Problem constants
#define N_ROWS 32768      // 16*2048 query vectors
#define D_DIM  256        // embedding dim
#define K_CODES 8192      // codebook size

// Output layout (flat float32, reference return order)
#define OUT0_OFF 0                     // z_q_st [16,2048,256]
#define OUT1_OFF 8388608               // z_q    [16,2048,256]
#define OUTI_OFF 16777216              // indices [16,2048] (as float)
#define OUTS_OFF 16809984              // stats [2]

typedef _Float16 half4 __attribute__((ext_vector_type(4)));
typedef _Float16 half8 __attribute__((ext_vector_type(8)));
typedef float    f32x16 __attribute__((ext_vector_type(16)));

// Staged-E image: 128 groups of 64 codes. Per group: 2 stages (d 0..127 /
// 128..255). Per stage: hi half [0,16384) + lo half [16384,32768): 64 rows
// of 256 B; 16-B slot s of row c holds dgroup (s - c) & 15 (rotate swizzle
// -> phase-optimal ds_read_b128, no padding, byte-copy staging).
#define ESTG_BYTES (128 * 65536)       // 8 MB, lives in out0 region
#define HN_OFF ESTG_BYTES              // -0.5*||e||^2 per code (32 KB)
#define XL_OFF 16777216                // Xl offset inside Xh region (bytes)

// ---------------------------------------------------------------------------
// Kernel 1: convert codebook -> staged fp16 split image + folded half-norms.
// 1 wave per code row. Also zeroes the usage histogram.
__global__ __launch_bounds__(256) void vq_conv_e(const float* __restrict__ E,
                                                 char* __restrict__ Estg,
                                                 float* __restrict__ hn,
                                                 int* __restrict__ usage) {
    const int wv = threadIdx.x >> 6;
    const int l = threadIdx.x & 63;
    const int code = blockIdx.x * 4 + wv;
    float4 v = ((const float4*)E)[code * 64 + l];  // d = 4l..4l+3

    const int g = code >> 6, c = code & 63;
    const int st = l >> 5;                  // d>=128 -> stage 1
    const int dg = ((4 * l) & 127) >> 3;    // dgroup within stage (0..15)
    const int slot = (dg + c) & 15;         // rotate swizzle
    const int sub = 8 * (l & 1);            // low/high half of the 16-B slot

    half4 hh = {(_Float16)v.x, (_Float16)v.y, (_Float16)v.z, (_Float16)v.w};
    half4 hl = {(_Float16)((v.x - (float)hh[0]) * 2048.0f),
                (_Float16)((v.y - (float)hh[1]) * 2048.0f),
                (_Float16)((v.z - (float)hh[2]) * 2048.0f),
                (_Float16)((v.w - (float)hh[3]) * 2048.0f)};

    char* p = Estg + (size_t)g * 65536 + st * 32768 + c * 256 + slot * 16 + sub;
    *(half4*)p = hh;
    *(half4*)(p + 16384) = hl;

    float s = v.x * v.x + v.y * v.y + v.z * v.z + v.w * v.w;
    #pragma unroll
    for (int off = 32; off >= 1; off >>= 1) s += __shfl_down(s, off);
    if (l == 0) hn[code] = -0.5f * s;

    if (blockIdx.x < K_CODES / 256) usage[blockIdx.x * 256 + threadIdx.x] = 0;
}

// ---------------------------------------------------------------------------
// Kernel 2: convert queries -> Xh / Xl' fp16 (natural [q][d] layout).
__global__ __launch_bounds__(256) void vq_conv_x(const float* __restrict__ x,
                                                 char* __restrict__ Xh) {
    const size_t i4 = ((size_t)blockIdx.x * 256 + threadIdx.x) * 4;
    float4 v = *(const float4*)(x + i4);
    half4 hh = {(_Float16)v.x, (_Float16)v.y, (_Float16)v.z, (_Float16)v.w};
    half4 hl = {(_Float16)((v.x - (float)hh[0]) * 2048.0f),
                (_Float16)((v.y - (float)hh[1]) * 2048.0f),
                (_Float16)((v.z - (float)hh[2]) * 2048.0f),
                (_Float16)((v.w - (float)hh[3]) * 2048.0f)};
    *(half4*)(Xh + i4 * 2) = hh;
    *(half4*)(Xh + XL_OFF + i4 * 2) = hl;
}

// ---------------------------------------------------------------------------
// Kernel 3: fused distance GEMM + argmin via MFMA (fp16 split-3).
// 256 blocks (1/CU) x 4 waves; wave owns 32 queries (X frags VGPR-resident);
// E streams through a 64 KB LDS double buffer (dbuf slot == d-stage).
#define STAGE_COMPUTE(STOFF)                                                   \
    _Pragma("unroll")                                                          \
    for (int ks = 0; ks < 8; ++ks) {                                           \
        const int slot = (2 * ks + hc) & 15;                                   \
        const int sa = rb0 + slot * 16 + (STOFF);                              \
        half8 ah0 = *(const half8*)(lds + sa);                                 \
        half8 al0 = *(const half8*)(lds + sa + 16384);                         \
        half8 ah1 = *(const half8*)(lds + sa + 8192);                          \
        half8 al1 = *(const half8*)(lds + sa + 24576);                         \
        const half8 bh = xhr[((STOFF) ? 8 : 0) + ks];                          \
        const half8 bl = xlr[((STOFF) ? 8 : 0) + ks];                          \
        accH0 = __builtin_amdgcn_mfma_f32_32x32x16_f16(ah0, bh, accH0, 0, 0, 0); \
        accH1 = __builtin_amdgcn_mfma_f32_32x32x16_f16(ah1, bh, accH1, 0, 0, 0); \
        accL0 = __builtin_amdgcn_mfma_f32_32x32x16_f16(ah0, bl, accL0, 0, 0, 0); \
        accL0 = __builtin_amdgcn_mfma_f32_32x32x16_f16(al0, bh, accL0, 0, 0, 0); \
        accL1 = __builtin_amdgcn_mfma_f32_32x32x16_f16(ah1, bl, accL1, 0, 0, 0); \
        accL1 = __builtin_amdgcn_mfma_f32_32x32x16_f16(al1, bh, accL1, 0, 0, 0); \
    }

#define LD_STAGE(dst, srcbase)                                                 \
    _Pragma("unroll") for (int i = 0; i < 8; ++i)                              \
        dst[i] = *(const float4*)((srcbase) + i * 4096);

#define WR_STAGE(src, BUFOFF)                                                  \
    _Pragma("unroll") for (int i = 0; i < 8; ++i)                              \
        *(float4*)(lds + (BUFOFF) + t16 + i * 4096) = src[i];

__global__ __launch_bounds__(256, 1) void vq_mfma(const char* __restrict__ Estg,
                                                  const float* __restrict__ hnp,
                                                  const char* __restrict__ Xh,
                                                  unsigned* __restrict__ idxws) {
    __shared__ __attribute__((aligned(16))) char lds[65536];

    const int tid = threadIdx.x;
    const int w = tid >> 6, lane = tid & 63;
    const int cl = lane & 31, half = lane >> 5;
    const int t16 = tid * 16;
    const int rb0 = cl * 256;       // row base for code tile 0 (tile 1 = +8192)
    const int hc = half + cl;       // swizzle key

    // --- prologue: X fragments resident (q = query column = cl) ---
    const int q = blockIdx.x * 128 + w * 32 + cl;
    const char* xb = Xh + (size_t)q * 512 + half * 16;
    half8 xhr[16], xlr[16];
    #pragma unroll
    for (int ks = 0; ks < 16; ++ks) {
        xhr[ks] = *(const half8*)(xb + ks * 32);
        xlr[ks] = *(const half8*)(xb + XL_OFF + ks * 32);
    }

    // --- prime staging: group 0 stages 0,1 ---
    float4 sv0[8], sv1[8];
    {
        const char* e0 = Estg + t16;
        LD_STAGE(sv0, e0)
        LD_STAGE(sv1, e0 + 32768)
        WR_STAGE(sv0, 0)           // stage 0 -> buf0
    }
    // prime hn for group 0
    float hncur[2][16], hnnext[2][16];
    #pragma unroll
    for (int t = 0; t < 2; ++t)
        #pragma unroll
        for (int r = 0; r < 16; ++r)
            hncur[t][r] = hnp[t * 32 + ((r & 3) + 8 * (r >> 2)) + 4 * half];

    float bestq = -3.4e38f;
    int besti = 0;

    for (int g = 0; g < 128; ++g) {
        // acc init: accHi = -0.5*||e||^2 folded in; accLo = 0
        f32x16 accH0, accH1, accL0, accL1;
        #pragma unroll
        for (int r = 0; r < 16; ++r) {
            accH0[r] = hncur[0][r];
            accH1[r] = hncur[1][r];
            accL0[r] = 0.0f;
            accL1[r] = 0.0f;
        }

        const char* esrc = Estg + (size_t)((g + 1) & 127) * 65536 + t16;
        const int hb = ((g + 1) & 127) * 64 + 4 * half;

        __syncthreads();                 // buf0 (stage 2g) ready; buf1 free
        WR_STAGE(sv1, 32768)             // stage 2g+1 -> buf1
        LD_STAGE(sv0, esrc)              // fetch stage 2g+2 (group g+1, st0)
        // prefetch half-norms for group g+1
        #pragma unroll
        for (int t = 0; t < 2; ++t)
            #pragma unroll
            for (int r = 0; r < 16; ++r)
                hnnext[t][r] = hnp[hb + t * 32 + ((r & 3) + 8 * (r >> 2))];
        STAGE_COMPUTE(0)                 // compute d 0..127 from buf0

        __syncthreads();                 // buf1 (stage 2g+1) ready; buf0 free
        WR_STAGE(sv0, 0)                 // stage 2g+2 -> buf0
        LD_STAGE(sv1, esrc + 32768)      // fetch stage 2g+3 (group g+1, st1)
        STAGE_COMPUTE(32768)             // compute d 128..255 from buf1

        // epilogue: q = accHi + 2^-11 * accLo == x.e - 0.5||e||^2 ; argmax
        const int ib = g * 64 + 4 * half;
        #pragma unroll
        for (int r = 0; r < 16; ++r) {
            const int rc = (r & 3) + 8 * (r >> 2);
            float q0 = fmaf(accL0[r], 4.8828125e-4f, accH0[r]);
            if (q0 > bestq) { bestq = q0; besti = ib + rc; }
            float q1 = fmaf(accL1[r], 4.8828125e-4f, accH1[r]);
            if (q1 > bestq) { bestq = q1; besti = ib + 32 + rc; }
        }

        #pragma unroll
        for (int t = 0; t < 2; ++t)
            #pragma unroll
            for (int r = 0; r < 16; ++r) hncur[t][r] = hnnext[t][r];
    }

    // merge the two half-lanes of each query column (tie -> lower index)
    float oq = __shfl(bestq, lane ^ 32);
    int oi = __shfl(besti, lane ^ 32);
    if (oq > bestq || (oq == bestq && oi < besti)) { bestq = oq; besti = oi; }
    if (lane < 32) idxws[blockIdx.x * 128 + w * 32 + lane] = (unsigned)besti;
}

// ---------------------------------------------------------------------------
// Kernel 4: gather codebook rows to z_q_st / z_q, emit float indices, usage.
__global__ __launch_bounds__(64) void vq_gather(const unsigned* __restrict__ idxws,
                                                const float* __restrict__ E,
                                                float* __restrict__ out0,
                                                float* __restrict__ out1,
                                                float* __restrict__ outI,
                                                int* __restrict__ usage) {
    const int row = blockIdx.x;
    const int lane = threadIdx.x;
    const unsigned idx = idxws[row];
    float4 e4 = ((const float4*)(E + (size_t)idx * D_DIM))[lane];
    ((float4*)(out0 + (size_t)row * D_DIM))[lane] = e4;
    ((float4*)(out1 + (size_t)row * D_DIM))[lane] = e4;
    if (lane == 0) {
        outI[row] = (float)idx;
        atomicAdd(&usage[idx], 1);
    }
}

// ---------------------------------------------------------------------------
// Kernel 5: perplexity + dead ratio. Single block.
__global__ __launch_bounds__(256) void vq_stats(const int* __restrict__ usage,
                                                float* __restrict__ statsOut) {
    __shared__ float redp[256];
    __shared__ int   redz[256];
    const int t = threadIdx.x;
    float pl = 0.0f;
    int zc = 0;
    for (int i = t; i < K_CODES; i += 256) {
        const int u = usage[i];
        if (u == 0) {
            zc++;
        } else {
            const float p = (float)u * (1.0f / (float)N_ROWS);
            pl += p * logf(p);
        }
    }
    redp[t] = pl;
    redz[t] = zc;
    __syncthreads();
    for (int s = 128; s > 0; s >>= 1) {
        if (t < s) { redp[t] += redp[t + s]; redz[t] += redz[t + s]; }
        __syncthreads();
    }
    if (t == 0) {
        statsOut[0] = expf(-redp[0]);
        statsOut[1] = (float)redz[0] / (float)K_CODES;
    }
}

// ---------------------------------------------------------------------------
extern "C" void kernel_launch(void* const* d_in, const int* in_sizes, int n_in,
                              void* d_out, int out_size, void* d_ws, size_t ws_size,
                              hipStream_t stream) {
    const float* z_e = (const float*)d_in[0];   // [16,2048,256] f32
    const float* E   = (const float*)d_in[1];   // [8192,256] f32

    float* out   = (float*)d_out;
    char*  out_b = (char*)d_out;

    // scratch in output regions (overwritten by gather at the end):
    char*  Estg = out_b;                          // [0, 8 MB) of out0 region
    float* hn   = (float*)(out_b + HN_OFF);       // 32 KB
    char*  Xh   = out_b + (size_t)OUT1_OFF * 4;   // out1 region: Xh | Xl

    float* out0 = out + OUT0_OFF;
    float* out1 = out + OUT1_OFF;
    float* outI = out + OUTI_OFF;
    float* outS = out + OUTS_OFF;

    int*      usage = (int*)d_ws;                          // 32 KB
    unsigned* idxws = (unsigned*)((char*)d_ws + 32768);    // 128 KB

    vq_conv_e<<<dim3(K_CODES / 4), dim3(256), 0, stream>>>(E, Estg, hn, usage);
    vq_conv_x<<<dim3(8192), dim3(256), 0, stream>>>(z_e, Xh);
    vq_mfma<<<dim3(256), dim3(256), 0, stream>>>(Estg, hn, Xh, idxws);
    vq_gather<<<dim3(N_ROWS), dim3(64), 0, stream>>>(idxws, E, out0, out1, outI, usage);
    vq_stats<<<dim3(1), dim3(256), 0, stream>>>(usage, outS);
}

// Round 4
// 478.675 us; speedup vs baseline: 16.0373x; 2.3528x over previous
//
#include <hip/hip_runtime.h>

// Problem constants
#define N_ROWS 32768      // 16*2048 query vectors
#define D_DIM  256        // embedding dim
#define K_CODES 8192      // codebook size

// Output layout (flat float32, reference return order)
#define OUT0_OFF 0                     // z_q_st [16,2048,256]
#define OUT1_OFF 8388608               // z_q    [16,2048,256]
#define OUTI_OFF 16777216              // indices [16,2048] (as float)
#define OUTS_OFF 16809984              // stats [2]

typedef _Float16 half4 __attribute__((ext_vector_type(4)));
typedef _Float16 half8 __attribute__((ext_vector_type(8)));
typedef float    f32x16 __attribute__((ext_vector_type(16)));

// Staged-E image: 128 groups of 64 codes. Per group: 2 stages (d 0..127 /
// 128..255). Per stage: hi half [0,16384) + lo half [16384,32768): 64 rows
// of 256 B; 16-B slot s of row c holds dgroup (s - c) & 15 (rotate swizzle
// -> phase-optimal ds_read_b128, no padding, byte-identity staging).
#define ESTG_BYTES (128 * 65536)       // 8 MB, lives in out0 region
#define HN_OFF ESTG_BYTES              // -0.5*||e||^2 per code (32 KB)
#define XL_OFF 16777216                // Xl offset inside Xh region (bytes)

// ---------------------------------------------------------------------------
// Kernel 1: convert codebook -> staged fp16 split image + folded half-norms.
__global__ __launch_bounds__(256) void vq_conv_e(const float* __restrict__ E,
                                                 char* __restrict__ Estg,
                                                 float* __restrict__ hn,
                                                 int* __restrict__ usage) {
    const int wv = threadIdx.x >> 6;
    const int l = threadIdx.x & 63;
    const int code = blockIdx.x * 4 + wv;
    float4 v = ((const float4*)E)[code * 64 + l];  // d = 4l..4l+3

    const int g = code >> 6, c = code & 63;
    const int st = l >> 5;                  // d>=128 -> stage 1
    const int dg = ((4 * l) & 127) >> 3;    // dgroup within stage (0..15)
    const int slot = (dg + c) & 15;         // rotate swizzle
    const int sub = 8 * (l & 1);            // low/high half of the 16-B slot

    half4 hh = {(_Float16)v.x, (_Float16)v.y, (_Float16)v.z, (_Float16)v.w};
    half4 hl = {(_Float16)((v.x - (float)hh[0]) * 2048.0f),
                (_Float16)((v.y - (float)hh[1]) * 2048.0f),
                (_Float16)((v.z - (float)hh[2]) * 2048.0f),
                (_Float16)((v.w - (float)hh[3]) * 2048.0f)};

    char* p = Estg + (size_t)g * 65536 + st * 32768 + c * 256 + slot * 16 + sub;
    *(half4*)p = hh;
    *(half4*)(p + 16384) = hl;

    float s = v.x * v.x + v.y * v.y + v.z * v.z + v.w * v.w;
    #pragma unroll
    for (int off = 32; off >= 1; off >>= 1) s += __shfl_down(s, off);
    if (l == 0) hn[code] = -0.5f * s;

    if (blockIdx.x < K_CODES / 256) usage[blockIdx.x * 256 + threadIdx.x] = 0;
}

// ---------------------------------------------------------------------------
// Kernel 2: convert queries -> Xh / Xl' fp16 (natural [q][d] layout).
__global__ __launch_bounds__(256) void vq_conv_x(const float* __restrict__ x,
                                                 char* __restrict__ Xh) {
    const size_t i4 = ((size_t)blockIdx.x * 256 + threadIdx.x) * 4;
    float4 v = *(const float4*)(x + i4);
    half4 hh = {(_Float16)v.x, (_Float16)v.y, (_Float16)v.z, (_Float16)v.w};
    half4 hl = {(_Float16)((v.x - (float)hh[0]) * 2048.0f),
                (_Float16)((v.y - (float)hh[1]) * 2048.0f),
                (_Float16)((v.z - (float)hh[2]) * 2048.0f),
                (_Float16)((v.w - (float)hh[3]) * 2048.0f)};
    *(half4*)(Xh + i4 * 2) = hh;
    *(half4*)(Xh + XL_OFF + i4 * 2) = hl;
}

// ---------------------------------------------------------------------------
// Kernel 3: fused distance GEMM + argmin via MFMA (fp16 split-3).
// Grid 512 = 256 query-blocks x 2 code-parts (part = blockIdx.x & 1 so a
// round-robin XCD mapping keeps one 4 MB E-partition per XCD L2).
// 4 waves/block; wave owns 32 queries (X frags VGPR-resident); E streams
// through a 64 KB LDS double buffer via global_load_lds (no VGPR staging).
#define STAGE_COMPUTE(STOFF)                                                   \
    _Pragma("unroll")                                                          \
    for (int ks = 0; ks < 8; ++ks) {                                           \
        const int slot = (2 * ks + hc) & 15;                                   \
        const int sa = rb0 + slot * 16 + (STOFF);                              \
        half8 ah0 = *(const half8*)(lds + sa);                                 \
        half8 al0 = *(const half8*)(lds + sa + 16384);                         \
        half8 ah1 = *(const half8*)(lds + sa + 8192);                          \
        half8 al1 = *(const half8*)(lds + sa + 24576);                         \
        const half8 bh = xhr[((STOFF) ? 8 : 0) + ks];                          \
        const half8 bl = xlr[((STOFF) ? 8 : 0) + ks];                          \
        accH0 = __builtin_amdgcn_mfma_f32_32x32x16_f16(ah0, bh, accH0, 0, 0, 0); \
        accH1 = __builtin_amdgcn_mfma_f32_32x32x16_f16(ah1, bh, accH1, 0, 0, 0); \
        accL0 = __builtin_amdgcn_mfma_f32_32x32x16_f16(ah0, bl, accL0, 0, 0, 0); \
        accL0 = __builtin_amdgcn_mfma_f32_32x32x16_f16(al0, bh, accL0, 0, 0, 0); \
        accL1 = __builtin_amdgcn_mfma_f32_32x32x16_f16(ah1, bl, accL1, 0, 0, 0); \
        accL1 = __builtin_amdgcn_mfma_f32_32x32x16_f16(al1, bh, accL1, 0, 0, 0); \
    }

// async global->LDS: 16 B per lane; LDS dest = wave-uniform base + lane*16.
#define ISSUE_STAGE(gsrc, BUFOFF)                                              \
    _Pragma("unroll") for (int i = 0; i < 8; ++i)                              \
        __builtin_amdgcn_global_load_lds(                                      \
            (const __attribute__((address_space(1))) void*)((gsrc) + i * 4096 + t16), \
            (__attribute__((address_space(3))) void*)(lds + (BUFOFF) + i * 4096 + t16), \
            16, 0, 0);

__global__ __launch_bounds__(256, 2) void vq_mfma(const char* __restrict__ Estg,
                                                  const float* __restrict__ hnp,
                                                  const char* __restrict__ Xh,
                                                  float* __restrict__ pv,
                                                  int* __restrict__ pi) {
    __shared__ __attribute__((aligned(16))) char lds[65536];

    const int tid = threadIdx.x;
    const int w = tid >> 6, lane = tid & 63;
    const int cl = lane & 31, half = lane >> 5;
    const int t16 = tid * 16;
    const int rb0 = cl * 256;       // row base for code tile 0 (tile 1 = +8192)
    const int hc = half + cl;       // swizzle key

    const int part = blockIdx.x & 1;        // code partition (4096 codes)
    const int qb = blockIdx.x >> 1;         // query block (128 queries)
    const char* Ebase = Estg + (size_t)part * 64 * 65536;

    // --- prologue: X fragments resident (q = query column = cl) ---
    const int q = qb * 128 + w * 32 + cl;
    const char* xb = Xh + (size_t)q * 512 + half * 16;
    half8 xhr[16], xlr[16];
    #pragma unroll
    for (int ks = 0; ks < 16; ++ks) {
        xhr[ks] = *(const half8*)(xb + ks * 32);
        xlr[ks] = *(const half8*)(xb + XL_OFF + ks * 32);
    }

    // prime: group 0 stage 0 -> buf0
    ISSUE_STAGE(Ebase, 0)

    float bestq = -3.4e38f;
    int besti = 0;

    for (int g = 0; g < 64; ++g) {
        const char* egrp = Ebase + (size_t)g * 65536;
        const char* enxt = Ebase + (size_t)((g + 1) & 63) * 65536;

        f32x16 accH0 = {}, accH1 = {}, accL0 = {}, accL1 = {};

        __syncthreads();                 // buf0 (stage 2g) landed; buf1 free
        ISSUE_STAGE(egrp + 32768, 32768) // stage 2g+1 -> buf1
        // per-lane half-norm prefetch for this group's epilogue (L2-hot)
        const float* hq = hnp + part * 4096 + g * 64 + 4 * half;
        float4 hn0[4], hn1[4];
        #pragma unroll
        for (int j = 0; j < 4; ++j) {
            hn0[j] = *(const float4*)(hq + 8 * j);
            hn1[j] = *(const float4*)(hq + 32 + 8 * j);
        }
        STAGE_COMPUTE(0)                 // compute d 0..127 from buf0

        __syncthreads();                 // buf1 landed; buf0 free
        ISSUE_STAGE(enxt, 0)             // group g+1 stage 0 -> buf0
        STAGE_COMPUTE(32768)             // compute d 128..255 from buf1

        // epilogue: q = accHi + 2^-11*accLo + (-0.5||e||^2); argmax
        const int ib = part * 4096 + g * 64 + 4 * half;
        #pragma unroll
        for (int r = 0; r < 16; ++r) {
            const int rc = (r & 3) + 8 * (r >> 2);
            float q0 = fmaf(accL0[r], 4.8828125e-4f, accH0[r]) + hn0[r >> 2][r & 3];
            if (q0 > bestq) { bestq = q0; besti = ib + rc; }
            float q1 = fmaf(accL1[r], 4.8828125e-4f, accH1[r]) + hn1[r >> 2][r & 3];
            if (q1 > bestq) { bestq = q1; besti = ib + 32 + rc; }
        }
    }

    // merge the two half-lanes of each query column (tie -> lower index)
    float oq = __shfl(bestq, lane ^ 32);
    int oi = __shfl(besti, lane ^ 32);
    if (oq > bestq || (oq == bestq && oi < besti)) { bestq = oq; besti = oi; }
    if (lane < 32) {
        pv[(size_t)(qb * 128 + w * 32 + lane) * 2 + part] = bestq;
        pi[(size_t)(qb * 128 + w * 32 + lane) * 2 + part] = besti;
    }
}

// ---------------------------------------------------------------------------
// Kernel 4: reduce the 2 code-part partials, gather codebook rows to
// z_q_st / z_q, emit float indices, bump usage histogram.
__global__ __launch_bounds__(64) void vq_gather(const float* __restrict__ pv,
                                                const int* __restrict__ pi,
                                                const float* __restrict__ E,
                                                float* __restrict__ out0,
                                                float* __restrict__ out1,
                                                float* __restrict__ outI,
                                                int* __restrict__ usage) {
    const int row = blockIdx.x;
    const int lane = threadIdx.x;
    const float q0 = pv[(size_t)row * 2 + 0];
    const float q1 = pv[(size_t)row * 2 + 1];
    // strict > : tie keeps part 0 (lower index), matching argmin-first
    const int idx = (q1 > q0) ? pi[(size_t)row * 2 + 1] : pi[(size_t)row * 2 + 0];

    float4 e4 = ((const float4*)(E + (size_t)idx * D_DIM))[lane];
    ((float4*)(out0 + (size_t)row * D_DIM))[lane] = e4;
    ((float4*)(out1 + (size_t)row * D_DIM))[lane] = e4;
    if (lane == 0) {
        outI[row] = (float)idx;
        atomicAdd(&usage[idx], 1);
    }
}

// ---------------------------------------------------------------------------
// Kernel 5: perplexity + dead ratio. Single block.
__global__ __launch_bounds__(256) void vq_stats(const int* __restrict__ usage,
                                                float* __restrict__ statsOut) {
    __shared__ float redp[256];
    __shared__ int   redz[256];
    const int t = threadIdx.x;
    float pl = 0.0f;
    int zc = 0;
    for (int i = t; i < K_CODES; i += 256) {
        const int u = usage[i];
        if (u == 0) {
            zc++;
        } else {
            const float p = (float)u * (1.0f / (float)N_ROWS);
            pl += p * logf(p);
        }
    }
    redp[t] = pl;
    redz[t] = zc;
    __syncthreads();
    for (int s = 128; s > 0; s >>= 1) {
        if (t < s) { redp[t] += redp[t + s]; redz[t] += redz[t + s]; }
        __syncthreads();
    }
    if (t == 0) {
        statsOut[0] = expf(-redp[0]);
        statsOut[1] = (float)redz[0] / (float)K_CODES;
    }
}

// ---------------------------------------------------------------------------
extern "C" void kernel_launch(void* const* d_in, const int* in_sizes, int n_in,
                              void* d_out, int out_size, void* d_ws, size_t ws_size,
                              hipStream_t stream) {
    const float* z_e = (const float*)d_in[0];   // [16,2048,256] f32
    const float* E   = (const float*)d_in[1];   // [8192,256] f32

    float* out   = (float*)d_out;
    char*  out_b = (char*)d_out;

    // scratch in output regions (overwritten by gather at the end):
    char*  Estg = out_b;                          // [0, 8 MB) of out0 region
    float* hn   = (float*)(out_b + HN_OFF);       // 32 KB
    char*  Xh   = out_b + (size_t)OUT1_OFF * 4;   // out1 region: Xh | Xl

    float* out0 = out + OUT0_OFF;
    float* out1 = out + OUT1_OFF;
    float* outI = out + OUTI_OFF;
    float* outS = out + OUTS_OFF;

    int*   usage = (int*)d_ws;                                   // 32 KB
    float* pv    = (float*)((char*)d_ws + 32768);                // 256 KB
    int*   pi    = (int*)((char*)d_ws + 32768 + 262144);         // 256 KB

    vq_conv_e<<<dim3(K_CODES / 4), dim3(256), 0, stream>>>(E, Estg, hn, usage);
    vq_conv_x<<<dim3(8192), dim3(256), 0, stream>>>(z_e, Xh);
    vq_mfma<<<dim3(512), dim3(256), 0, stream>>>(Estg, hn, Xh, pv, pi);
    vq_gather<<<dim3(N_ROWS), dim3(64), 0, stream>>>(pv, pi, E, out0, out1, outI, usage);
    vq_stats<<<dim3(1), dim3(256), 0, stream>>>(usage, outS);
}